// Round 9
// baseline (214.993 us; speedup 1.0000x reference)
//
#include <hip/hip_runtime.h>

#define KF    16
#define DIM   64

typedef __attribute__((ext_vector_type(8))) short bs8;    // 8 bf16 (4 VGPRs)
typedef __attribute__((ext_vector_type(4))) float f32x4;  // MFMA accumulator

// Compiler-order fence (TBAA may judge ushort stores vs bs8 loads NoAlias).
#define C_FENCE() do { asm volatile("" ::: "memory"); \
                       __builtin_amdgcn_sched_barrier(0); } while (0)

__device__ __forceinline__ float fsig(float x) {
    return __builtin_amdgcn_rcpf(1.0f + __expf(-x));
}
__device__ __forceinline__ float ftanh(float x) {
    float e = __expf(2.0f * x);
    return 1.0f - 2.0f * __builtin_amdgcn_rcpf(e + 1.0f);
}
__device__ __forceinline__ ushort f2bf(float x) {         // f32 -> bf16 bits, RNE
    uint u = __builtin_bit_cast(uint, x);
    u += 0x7fffu + ((u >> 16) & 1u);
    return (ushort)(u >> 16);
}
__device__ __forceinline__ float rdlane_f(float v, int l) {
    return __builtin_bit_cast(float, __builtin_amdgcn_readlane(__builtin_bit_cast(int, v), l));
}

// 16-lane-group softmax (groups of lanes with equal lane>>4): input score, output weight
__device__ __forceinline__ float softmax16(float sc) {
    float mx = sc;
    mx = fmaxf(mx, __shfl_xor(mx, 1));
    mx = fmaxf(mx, __shfl_xor(mx, 2));
    mx = fmaxf(mx, __shfl_xor(mx, 4));
    mx = fmaxf(mx, __shfl_xor(mx, 8));
    float e  = __expf(sc - mx);
    float sm = e;
    sm += __shfl_xor(sm, 1);
    sm += __shfl_xor(sm, 2);
    sm += __shfl_xor(sm, 4);
    sm += __shfl_xor(sm, 8);
    return e * __builtin_amdgcn_rcpf(sm);
}

// ================= phase A0: per-element urs[32] + e1 row =================
__global__ __launch_bounds__(256) void k_pre(
    const int* __restrict__ u, const int* __restrict__ v,
    const int* __restrict__ adj_ent,
    const float* __restrict__ usr_emb, const float* __restrict__ rel_emb,
    float* __restrict__ urs_ws, int* __restrict__ e1_ws)
{
    const int lane = threadIdx.x & 63, wv = threadIdx.x >> 6;
    const int b  = blockIdx.x * 4 + wv;
    const int e0 = v[b];
    const int e1 = adj_ent[e0 * KF + (lane & 15)];
    const float user = usr_emb[(size_t)u[b] * DIM + lane];
    const int r = lane & 31, hb = lane & 32;
    float s = 0.0f;
    #pragma unroll
    for (int dd = 0; dd < 32; ++dd)
        s = fmaf(__shfl(user, hb + dd), rel_emb[r * DIM + hb + dd], s);
    s += __shfl_xor(s, 32);
    if (lane < 32) urs_ws[b * 32 + lane] = s;
    if (lane < KF) e1_ws[b * KF + lane] = e1;
}

// ================= phase A: one wave per hop-1 node -> X row ==============
__global__ __launch_bounds__(256) void k_nodes(
    const int* __restrict__ adj_ent, const int* __restrict__ adj_rel,
    const float* __restrict__ ent_emb,
    const float* __restrict__ urs_ws, const int* __restrict__ e1_ws,
    ushort* __restrict__ Xws)
{
    const int lane = threadIdx.x & 63, wv = threadIdx.x >> 6;
    const int gw = blockIdx.x * 4 + wv;      // node id = b*16 + m
    const int b  = gw >> 4;
    const int lr = lane & 15;

    const int e1m = e1_ws[gw];
    // issue index loads + self row early
    const int e2v = adj_ent[e1m * KF + lr];  // lane lr holds e2[lr] (x4 copies)
    const int r2  = adj_rel[e1m * KF + lr];
    float rows[KF + 1];
    rows[KF] = ent_emb[(size_t)e1m * DIM + lane];
    #pragma unroll
    for (int k = 0; k < KF; ++k) {
        const int e = __builtin_amdgcn_readlane(e2v, k);
        rows[k] = ent_emb[(size_t)e * DIM + lane];
    }
    // at2 softmax overlaps gather latency
    const float at2v = softmax16(urs_ws[b * 32 + r2]);

    float g0 = 0.0f, g1 = 0.0f, g2 = 0.0f, g3 = 0.0f;
    #pragma unroll
    for (int k = 0; k < KF; k += 4) {
        g0 = fmaf(rdlane_f(at2v, k + 0), rows[k + 0], g0);
        g1 = fmaf(rdlane_f(at2v, k + 1), rows[k + 1], g1);
        g2 = fmaf(rdlane_f(at2v, k + 2), rows[k + 2], g2);
        g3 = fmaf(rdlane_f(at2v, k + 3), rows[k + 3], g3);
    }
    Xws[(size_t)gw * DIM + lane] = f2bf(rows[KF] + ((g0 + g1) + (g2 + g3)));
}

// ================= phase B: per-element MFMA tail =========================
__global__ __launch_bounds__(256) void k_tail(
    const int* __restrict__ u, const int* __restrict__ v,
    const int* __restrict__ adj_rel,
    const float* __restrict__ usr_emb, const float* __restrict__ ent_emb,
    const float* __restrict__ W, const float* __restrict__ bias,
    const float* __restrict__ urs_ws, const int* __restrict__ e1_ws,
    const ushort* __restrict__ Xws, float* __restrict__ out)
{
    __shared__ __align__(16) ushort Wfrag[2][4][64][8];   // 8 KB
    __shared__ __align__(16) ushort Xl[4][16][72];        // 9 KB (row 0 live only)

    const int tid  = threadIdx.x;
    const int lane = tid & 63;
    const int wv   = tid >> 6;
    const int lr   = lane & 15;
    const int lg   = lane >> 4;

    {   // stage W fragments (wave wv stages tile t = wv)
        const int col = wv * 16 + lr;
        bs8 p0, p1;
        #pragma unroll
        for (int i = 0; i < 8; ++i) {
            p0[i] = (short)f2bf(W[(lg * 8 + i) * DIM + col]);
            p1[i] = (short)f2bf(W[(lg * 8 + i + 32) * DIM + col]);
        }
        *(bs8*)&Wfrag[0][wv][lane][0] = p0;
        *(bs8*)&Wfrag[1][wv][lane][0] = p1;
    }
    const float biasr = bias[lane];
    __syncthreads();   // B0: Wfrag visible (only block-wide barrier)

    const int   b     = blockIdx.x * 4 + wv;
    const int   e0    = v[b];
    const float user  = usr_emb[(size_t)u[b] * DIM + lane];
    const float ent0v = ent_emb[(size_t)e0 * DIM + lane];

    // hop-0 index row + gathers (issue early)
    const int e1r = e1_ws[b * KF + lr];      // lane lr holds e1[lr] (x4 copies)
    float rows[KF];
    #pragma unroll
    for (int k = 0; k < KF; ++k) {
        const int e = __builtin_amdgcn_readlane(e1r, k);
        rows[k] = ent_emb[(size_t)e * DIM + lane];
    }
    // X A-fragments straight from global (ws layout == A-fragment layout)
    const bs8 a0 = *(const bs8*)&Xws[((size_t)b * KF + lr) * DIM + lg * 8];
    const bs8 a1 = *(const bs8*)&Xws[((size_t)b * KF + lr) * DIM + lg * 8 + 32];

    // at1 softmax
    const int r1 = adj_rel[e0 * KF + lr];
    const float at1r = softmax16(urs_ws[b * 32 + r1]);

    // agg0 (lane = d)
    float g0 = 0.0f, g1 = 0.0f, g2 = 0.0f, g3 = 0.0f;
    #pragma unroll
    for (int k = 0; k < KF; k += 4) {
        g0 = fmaf(rdlane_f(at1r, k + 0), rows[k + 0], g0);
        g1 = fmaf(rdlane_f(at1r, k + 1), rows[k + 1], g1);
        g2 = fmaf(rdlane_f(at1r, k + 2), rows[k + 2], g2);
        g3 = fmaf(rdlane_f(at1r, k + 3), rows[k + 3], g3);
    }
    const float x0 = ent0v + ((g0 + g1) + (g2 + g3));

    float bj[4];
    #pragma unroll
    for (int t = 0; t < 4; ++t) bj[t] = __shfl(biasr, t * 16 + lr);

    // P1: h1 = sig(X@W+b); agg2 per tile
    float agg2r[4];
    #pragma unroll
    for (int t = 0; t < 4; ++t) {
        f32x4 c; c[0] = bj[t]; c[1] = bj[t]; c[2] = bj[t]; c[3] = bj[t];
        const bs8 w0 = *(const bs8*)&Wfrag[0][t][lane][0];
        const bs8 w1 = *(const bs8*)&Wfrag[1][t][lane][0];
        c = __builtin_amdgcn_mfma_f32_16x16x32_bf16(a0, w0, c, 0, 0, 0);
        c = __builtin_amdgcn_mfma_f32_16x16x32_bf16(a1, w1, c, 0, 0, 0);
        float p = 0.0f;                     // sum_m at1[m]*sig(C[m][col]); row = lg*4+r
        #pragma unroll
        for (int r = 0; r < 4; ++r)
            p = fmaf(__shfl(at1r, lg * 4 + r), fsig(c[r]), p);
        p += __shfl_xor(p, 16);
        p += __shfl_xor(p, 32);
        agg2r[t] = p;
    }

    Xl[wv][0][lane] = f2bf(x0);             // x0 into row 0 (rows 1-15 garbage, unused)
    C_FENCE();                              // x0 store before P2 reads (RAW)

    // P2: h0 via MFMA on row 0
    float x2v[4];
    {
        const bs8 b0 = *(const bs8*)&Xl[wv][lr][lg * 8];
        const bs8 b1 = *(const bs8*)&Xl[wv][lr][lg * 8 + 32];
        #pragma unroll
        for (int t = 0; t < 4; ++t) {
            f32x4 c; c[0] = bj[t]; c[1] = bj[t]; c[2] = bj[t]; c[3] = bj[t];
            const bs8 w0 = *(const bs8*)&Wfrag[0][t][lane][0];
            const bs8 w1 = *(const bs8*)&Wfrag[1][t][lane][0];
            c = __builtin_amdgcn_mfma_f32_16x16x32_bf16(b0, w0, c, 0, 0, 0);
            c = __builtin_amdgcn_mfma_f32_16x16x32_bf16(b1, w1, c, 0, 0, 0);
            x2v[t] = fsig(c[0]) + agg2r[t]; // meaningful at lanes<16 (row 0)
        }
    }

    C_FENCE();                              // P2 loads BEFORE x2 stores (WAR)
    #pragma unroll
    for (int t = 0; t < 4; ++t)
        if (lane < 16) Xl[wv][0][t * 16 + lane] = f2bf(x2v[t]);
    C_FENCE();                              // x2 stores before P3 reads (RAW)

    // P3: item via MFMA + final dot
    float pv = 0.0f;
    {
        const bs8 b0 = *(const bs8*)&Xl[wv][lr][lg * 8];
        const bs8 b1 = *(const bs8*)&Xl[wv][lr][lg * 8 + 32];
        #pragma unroll
        for (int t = 0; t < 4; ++t) {
            f32x4 c; c[0] = bj[t]; c[1] = bj[t]; c[2] = bj[t]; c[3] = bj[t];
            const bs8 w0 = *(const bs8*)&Wfrag[0][t][lane][0];
            const bs8 w1 = *(const bs8*)&Wfrag[1][t][lane][0];
            c = __builtin_amdgcn_mfma_f32_16x16x32_bf16(b0, w0, c, 0, 0, 0);
            c = __builtin_amdgcn_mfma_f32_16x16x32_bf16(b1, w1, c, 0, 0, 0);
            const float uc = __shfl(user, t * 16 + lr);
            if (lane < 16) pv = fmaf(uc, ftanh(c[0]), pv);
        }
    }
    pv += __shfl_xor(pv, 1);
    pv += __shfl_xor(pv, 2);
    pv += __shfl_xor(pv, 4);
    pv += __shfl_xor(pv, 8);
    if (lane == 0) out[b] = fsig(pv);
}

// ============ fallback: round-8 fused kernel (ws too small) ==============
__global__ __launch_bounds__(256) void kgcn_fused(
    const int* __restrict__ u, const int* __restrict__ v,
    const int* __restrict__ adj_ent, const int* __restrict__ adj_rel,
    const float* __restrict__ usr_emb, const float* __restrict__ rel_emb,
    const float* __restrict__ ent_emb, const float* __restrict__ W,
    const float* __restrict__ bias, float* __restrict__ out, int B)
{
    __shared__ __align__(16) ushort Wfrag[2][4][64][8];
    __shared__ __align__(16) ushort Xl[4][16][72];

    const int tid  = threadIdx.x;
    const int lane = tid & 63;
    const int wv   = tid >> 6;
    const int lr   = lane & 15;
    const int lg   = lane >> 4;

    {
        const int col = wv * 16 + lr;
        bs8 p0, p1;
        #pragma unroll
        for (int i = 0; i < 8; ++i) {
            p0[i] = (short)f2bf(W[(lg * 8 + i) * DIM + col]);
            p1[i] = (short)f2bf(W[(lg * 8 + i + 32) * DIM + col]);
        }
        *(bs8*)&Wfrag[0][wv][lane][0] = p0;
        *(bs8*)&Wfrag[1][wv][lane][0] = p1;
    }
    const float biasr = bias[lane];
    __syncthreads();

    const int   b     = blockIdx.x * 4 + wv;
    const int   e0    = v[b];
    const float user  = usr_emb[(size_t)u[b] * DIM + lane];
    const float ent0v = ent_emb[(size_t)e0 * DIM + lane];

    float ursr;
    {
        const int r  = lane & 31;
        const int hb = lane & 32;
        float s = 0.0f;
        #pragma unroll
        for (int dd = 0; dd < 32; ++dd)
            s = fmaf(__shfl(user, hb + dd), rel_emb[r * DIM + hb + dd], s);
        s += __shfl_xor(s, 32);
        ursr = s;
    }
    int e1r; float at1r;
    {
        e1r = adj_ent[e0 * KF + lr];
        at1r = softmax16(__shfl(ursr, adj_rel[e0 * KF + lr]));
    }
    int e2r[4]; float at2r[4];
    #pragma unroll
    for (int it = 0; it < 4; ++it) {
        const int m  = it * 4 + lg;
        const int em = __shfl(e1r, m);
        e2r[it] = adj_ent[em * KF + lr];
        at2r[it] = softmax16(__shfl(ursr, adj_rel[em * KF + lr]));
    }

    float agg0p = 0.0f;
    #pragma unroll
    for (int qo = 0; qo < 4; ++qo) {
        #pragma unroll 1
        for (int qi = 0; qi < 4; ++qi) {
            const int q = qo * 4 + qi;
            float rows[KF + 1];
            #pragma unroll
            for (int k = 0; k < KF; ++k) {
                const int e = __builtin_amdgcn_readlane(e2r[qo], qi * 16 + k);
                rows[k] = ent_emb[(size_t)e * DIM + lane];
            }
            rows[KF] = ent_emb[(size_t)__builtin_amdgcn_readlane(e1r, q) * DIM + lane];
            float g0 = 0.0f, g1 = 0.0f, g2 = 0.0f, g3 = 0.0f;
            #pragma unroll
            for (int k = 0; k < KF; k += 4) {
                g0 = fmaf(rdlane_f(at2r[qo], qi * 16 + k + 0), rows[k + 0], g0);
                g1 = fmaf(rdlane_f(at2r[qo], qi * 16 + k + 1), rows[k + 1], g1);
                g2 = fmaf(rdlane_f(at2r[qo], qi * 16 + k + 2), rows[k + 2], g2);
                g3 = fmaf(rdlane_f(at2r[qo], qi * 16 + k + 3), rows[k + 3], g3);
            }
            agg0p = fmaf(rdlane_f(at1r, q), rows[KF], agg0p);
            Xl[wv][q][lane] = f2bf(rows[KF] + ((g0 + g1) + (g2 + g3)));
        }
    }
    C_FENCE();

    float bj[4];
    #pragma unroll
    for (int t = 0; t < 4; ++t) bj[t] = __shfl(biasr, t * 16 + lr);

    float agg2r[4];
    {
        const bs8 a0 = *(const bs8*)&Xl[wv][lr][lg * 8];
        const bs8 a1 = *(const bs8*)&Xl[wv][lr][lg * 8 + 32];
        #pragma unroll
        for (int t = 0; t < 4; ++t) {
            f32x4 c; c[0] = bj[t]; c[1] = bj[t]; c[2] = bj[t]; c[3] = bj[t];
            const bs8 w0 = *(const bs8*)&Wfrag[0][t][lane][0];
            const bs8 w1 = *(const bs8*)&Wfrag[1][t][lane][0];
            c = __builtin_amdgcn_mfma_f32_16x16x32_bf16(a0, w0, c, 0, 0, 0);
            c = __builtin_amdgcn_mfma_f32_16x16x32_bf16(a1, w1, c, 0, 0, 0);
            float p = 0.0f;
            #pragma unroll
            for (int r = 0; r < 4; ++r)
                p = fmaf(__shfl(at1r, lg * 4 + r), fsig(c[r]), p);
            p += __shfl_xor(p, 16);
            p += __shfl_xor(p, 32);
            agg2r[t] = p;
        }
    }
    C_FENCE();
    Xl[wv][0][lane] = f2bf(ent0v + agg0p);
    C_FENCE();
    float x2v[4];
    {
        const bs8 a0 = *(const bs8*)&Xl[wv][lr][lg * 8];
        const bs8 a1 = *(const bs8*)&Xl[wv][lr][lg * 8 + 32];
        #pragma unroll
        for (int t = 0; t < 4; ++t) {
            f32x4 c; c[0] = bj[t]; c[1] = bj[t]; c[2] = bj[t]; c[3] = bj[t];
            const bs8 w0 = *(const bs8*)&Wfrag[0][t][lane][0];
            const bs8 w1 = *(const bs8*)&Wfrag[1][t][lane][0];
            c = __builtin_amdgcn_mfma_f32_16x16x32_bf16(a0, w0, c, 0, 0, 0);
            c = __builtin_amdgcn_mfma_f32_16x16x32_bf16(a1, w1, c, 0, 0, 0);
            x2v[t] = fsig(c[0]) + agg2r[t];
        }
    }
    C_FENCE();
    #pragma unroll
    for (int t = 0; t < 4; ++t)
        if (lane < 16) Xl[wv][0][t * 16 + lane] = f2bf(x2v[t]);
    C_FENCE();
    float pv = 0.0f;
    {
        const bs8 a0 = *(const bs8*)&Xl[wv][lr][lg * 8];
        const bs8 a1 = *(const bs8*)&Xl[wv][lr][lg * 8 + 32];
        #pragma unroll
        for (int t = 0; t < 4; ++t) {
            f32x4 c; c[0] = bj[t]; c[1] = bj[t]; c[2] = bj[t]; c[3] = bj[t];
            const bs8 w0 = *(const bs8*)&Wfrag[0][t][lane][0];
            const bs8 w1 = *(const bs8*)&Wfrag[1][t][lane][0];
            c = __builtin_amdgcn_mfma_f32_16x16x32_bf16(a0, w0, c, 0, 0, 0);
            c = __builtin_amdgcn_mfma_f32_16x16x32_bf16(a1, w1, c, 0, 0, 0);
            const float uc = __shfl(user, t * 16 + lr);
            if (lane < 16) pv = fmaf(uc, ftanh(c[0]), pv);
        }
    }
    pv += __shfl_xor(pv, 1);
    pv += __shfl_xor(pv, 2);
    pv += __shfl_xor(pv, 4);
    pv += __shfl_xor(pv, 8);
    if (lane == 0) out[b] = fsig(pv);
}

extern "C" void kernel_launch(void* const* d_in, const int* in_sizes, int n_in,
                              void* d_out, int out_size, void* d_ws, size_t ws_size,
                              hipStream_t stream) {
    const int*   u       = (const int*)d_in[0];
    const int*   v       = (const int*)d_in[1];
    const int*   adj_ent = (const int*)d_in[2];
    const int*   adj_rel = (const int*)d_in[3];
    const float* usr_emb = (const float*)d_in[4];
    const float* rel_emb = (const float*)d_in[5];
    const float* ent_emb = (const float*)d_in[6];
    const float* W       = (const float*)d_in[7];
    const float* bias    = (const float*)d_in[8];
    float* out = (float*)d_out;

    const int B = in_sizes[0];

    // workspace layout: urs[B*32 f32] | e1[B*16 i32] | X[B*16*64 bf16]
    const size_t off_urs = 0;
    const size_t off_e1  = off_urs + (size_t)B * 32 * sizeof(float);
    const size_t off_X   = off_e1  + (size_t)B * KF * sizeof(int);
    const size_t need    = off_X   + (size_t)B * KF * DIM * sizeof(ushort);

    if (ws_size >= need) {
        float*  urs_ws = (float*)((char*)d_ws + off_urs);
        int*    e1_ws  = (int*)  ((char*)d_ws + off_e1);
        ushort* Xws    = (ushort*)((char*)d_ws + off_X);
        k_pre  <<<B / 4,          256, 0, stream>>>(u, v, adj_ent, usr_emb, rel_emb,
                                                    urs_ws, e1_ws);
        k_nodes<<<(B * KF) / 4,   256, 0, stream>>>(adj_ent, adj_rel, ent_emb,
                                                    urs_ws, e1_ws, Xws);
        k_tail <<<B / 4,          256, 0, stream>>>(u, v, adj_rel, usr_emb, ent_emb,
                                                    W, bias, urs_ws, e1_ws, Xws, out);
    } else {
        kgcn_fused<<<B / 4, 256, 0, stream>>>(u, v, adj_ent, adj_rel,
                                              usr_emb, rel_emb, ent_emb,
                                              W, bias, out, B);
    }
}

// Round 10
// 191.486 us; speedup vs baseline: 1.1228x; 1.1228x over previous
//
#include <hip/hip_runtime.h>

#define KF    16
#define DIM   64

typedef __attribute__((ext_vector_type(8))) short  bs8;   // 8 bf16 (4 VGPRs)
typedef __attribute__((ext_vector_type(8))) ushort us8;   // 8 bf16 bits
typedef __attribute__((ext_vector_type(4))) float  f32x4; // MFMA accumulator

// Compiler-order fence (TBAA may judge ushort stores vs bs8 loads NoAlias).
#define C_FENCE() do { asm volatile("" ::: "memory"); \
                       __builtin_amdgcn_sched_barrier(0); } while (0)

__device__ __forceinline__ float fsig(float x) {
    return __builtin_amdgcn_rcpf(1.0f + __expf(-x));
}
__device__ __forceinline__ float ftanh(float x) {
    float e = __expf(2.0f * x);
    return 1.0f - 2.0f * __builtin_amdgcn_rcpf(e + 1.0f);
}
__device__ __forceinline__ ushort f2bf(float x) {         // f32 -> bf16 bits, RNE
    uint u = __builtin_bit_cast(uint, x);
    u += 0x7fffu + ((u >> 16) & 1u);
    return (ushort)(u >> 16);
}
__device__ __forceinline__ float b2f(ushort b) {          // bf16 bits -> f32
    return __builtin_bit_cast(float, (uint)b << 16);
}
__device__ __forceinline__ float rdlane_f(float v, int l) {
    return __builtin_bit_cast(float, __builtin_amdgcn_readlane(__builtin_bit_cast(int, v), l));
}
__device__ __forceinline__ float softmax16(float sc) {    // per 16-lane group
    float mx = sc;
    mx = fmaxf(mx, __shfl_xor(mx, 1));
    mx = fmaxf(mx, __shfl_xor(mx, 2));
    mx = fmaxf(mx, __shfl_xor(mx, 4));
    mx = fmaxf(mx, __shfl_xor(mx, 8));
    float e  = __expf(sc - mx);
    float sm = e;
    sm += __shfl_xor(sm, 1);
    sm += __shfl_xor(sm, 2);
    sm += __shfl_xor(sm, 4);
    sm += __shfl_xor(sm, 8);
    return e * __builtin_amdgcn_rcpf(sm);
}

// ========== phase A0: ent_emb->bf16 convert (grid-stride chunk) + per-element pre ==========
__global__ __launch_bounds__(256) void k_convert_pre(
    const float* __restrict__ ent_emb, ushort* __restrict__ ent_bf, long n8,
    const int* __restrict__ u, const int* __restrict__ v,
    const int* __restrict__ adj_ent,
    const float* __restrict__ usr_emb, const float* __restrict__ rel_emb,
    float* __restrict__ urs_ws, int* __restrict__ e1_ws, int B)
{
    const long i = (long)blockIdx.x * 256 + threadIdx.x;
    if (i < n8) {
        const float4 f0 = ((const float4*)ent_emb)[2 * i];
        const float4 f1 = ((const float4*)ent_emb)[2 * i + 1];
        us8 o;
        o[0] = f2bf(f0.x); o[1] = f2bf(f0.y); o[2] = f2bf(f0.z); o[3] = f2bf(f0.w);
        o[4] = f2bf(f1.x); o[5] = f2bf(f1.y); o[6] = f2bf(f1.z); o[7] = f2bf(f1.w);
        ((us8*)ent_bf)[i] = o;
    }
    const int wv = threadIdx.x >> 6, lane = threadIdx.x & 63;
    const int b  = blockIdx.x * 4 + wv;
    if (b < B) {
        const int e0 = v[b];
        const int e1 = adj_ent[e0 * KF + (lane & 15)];
        const float user = usr_emb[(size_t)u[b] * DIM + lane];
        const int r = lane & 31, hb = lane & 32;
        float s = 0.0f;
        #pragma unroll
        for (int dd = 0; dd < 32; ++dd)
            s = fmaf(__shfl(user, hb + dd), rel_emb[r * DIM + hb + dd], s);
        s += __shfl_xor(s, 32);
        if (lane < 32) urs_ws[b * 32 + lane] = s;
        if (lane < KF) e1_ws[b * KF + lane] = e1;
    }
}

// ================= phase A: one wave per hop-1 node -> X row ==============
template<bool BF>
__global__ __launch_bounds__(256) void k_nodes(
    const int* __restrict__ adj_ent, const int* __restrict__ adj_rel,
    const float* __restrict__ entf, const ushort* __restrict__ entb,
    const float* __restrict__ urs_ws, const int* __restrict__ e1_ws,
    ushort* __restrict__ Xws)
{
    const int lane = threadIdx.x & 63, wv = threadIdx.x >> 6;
    const int gw = blockIdx.x * 4 + wv;      // node id = b*16 + m
    const int b  = gw >> 4;
    const int lr = lane & 15;

    const int e1m = e1_ws[gw];
    const int e2v = adj_ent[e1m * KF + lr];  // lane lr holds e2[lr] (x4 copies)
    const int r2  = adj_rel[e1m * KF + lr];
    float rows[KF + 1];
    rows[KF] = BF ? b2f(entb[(size_t)e1m * DIM + lane])
                  : entf[(size_t)e1m * DIM + lane];
    #pragma unroll
    for (int k = 0; k < KF; ++k) {
        const int e = __builtin_amdgcn_readlane(e2v, k);
        rows[k] = BF ? b2f(entb[(size_t)e * DIM + lane])
                     : entf[(size_t)e * DIM + lane];
    }
    const float at2v = softmax16(urs_ws[b * 32 + r2]);   // overlaps gather latency

    float g0 = 0.0f, g1 = 0.0f, g2 = 0.0f, g3 = 0.0f;
    #pragma unroll
    for (int k = 0; k < KF; k += 4) {
        g0 = fmaf(rdlane_f(at2v, k + 0), rows[k + 0], g0);
        g1 = fmaf(rdlane_f(at2v, k + 1), rows[k + 1], g1);
        g2 = fmaf(rdlane_f(at2v, k + 2), rows[k + 2], g2);
        g3 = fmaf(rdlane_f(at2v, k + 3), rows[k + 3], g3);
    }
    Xws[(size_t)gw * DIM + lane] = f2bf(rows[KF] + ((g0 + g1) + (g2 + g3)));
}

// ================= phase B: per-element MFMA tail =========================
template<bool BF>
__global__ __launch_bounds__(256) void k_tail(
    const int* __restrict__ u, const int* __restrict__ v,
    const int* __restrict__ adj_rel,
    const float* __restrict__ usr_emb,
    const float* __restrict__ entf, const ushort* __restrict__ entb,
    const float* __restrict__ W, const float* __restrict__ bias,
    const float* __restrict__ urs_ws, const int* __restrict__ e1_ws,
    const ushort* __restrict__ Xws, float* __restrict__ out)
{
    __shared__ __align__(16) ushort Wfrag[2][4][64][8];   // 8 KB
    __shared__ __align__(16) ushort Xl[4][16][72];        // 9 KB (row 0 live only)

    const int tid  = threadIdx.x;
    const int lane = tid & 63;
    const int wv   = tid >> 6;
    const int lr   = lane & 15;
    const int lg   = lane >> 4;

    {   // stage W fragments (wave wv stages tile t = wv)
        const int col = wv * 16 + lr;
        bs8 p0, p1;
        #pragma unroll
        for (int i = 0; i < 8; ++i) {
            p0[i] = (short)f2bf(W[(lg * 8 + i) * DIM + col]);
            p1[i] = (short)f2bf(W[(lg * 8 + i + 32) * DIM + col]);
        }
        *(bs8*)&Wfrag[0][wv][lane][0] = p0;
        *(bs8*)&Wfrag[1][wv][lane][0] = p1;
    }
    const float biasr = bias[lane];
    __syncthreads();   // B0: Wfrag visible (only block-wide barrier)

    const int   b    = blockIdx.x * 4 + wv;
    const int   e0   = v[b];
    const float user = usr_emb[(size_t)u[b] * DIM + lane];
    const float ent0v = BF ? b2f(entb[(size_t)e0 * DIM + lane])
                           : entf[(size_t)e0 * DIM + lane];

    // hop-0 index row + gathers (issue early)
    const int e1r = e1_ws[b * KF + lr];      // lane lr holds e1[lr] (x4 copies)
    float rows[KF];
    #pragma unroll
    for (int k = 0; k < KF; ++k) {
        const int e = __builtin_amdgcn_readlane(e1r, k);
        rows[k] = BF ? b2f(entb[(size_t)e * DIM + lane])
                     : entf[(size_t)e * DIM + lane];
    }
    // X A-fragments straight from global (ws layout == A-fragment layout)
    const bs8 a0 = *(const bs8*)&Xws[((size_t)b * KF + lr) * DIM + lg * 8];
    const bs8 a1 = *(const bs8*)&Xws[((size_t)b * KF + lr) * DIM + lg * 8 + 32];

    const int r1 = adj_rel[e0 * KF + lr];
    const float at1r = softmax16(urs_ws[b * 32 + r1]);

    // agg0 (lane = d)
    float g0 = 0.0f, g1 = 0.0f, g2 = 0.0f, g3 = 0.0f;
    #pragma unroll
    for (int k = 0; k < KF; k += 4) {
        g0 = fmaf(rdlane_f(at1r, k + 0), rows[k + 0], g0);
        g1 = fmaf(rdlane_f(at1r, k + 1), rows[k + 1], g1);
        g2 = fmaf(rdlane_f(at1r, k + 2), rows[k + 2], g2);
        g3 = fmaf(rdlane_f(at1r, k + 3), rows[k + 3], g3);
    }
    const float x0 = ent0v + ((g0 + g1) + (g2 + g3));

    float bj[4];
    #pragma unroll
    for (int t = 0; t < 4; ++t) bj[t] = __shfl(biasr, t * 16 + lr);

    // P1: h1 = sig(X@W+b); agg2 per tile
    float agg2r[4];
    #pragma unroll
    for (int t = 0; t < 4; ++t) {
        f32x4 c; c[0] = bj[t]; c[1] = bj[t]; c[2] = bj[t]; c[3] = bj[t];
        const bs8 w0 = *(const bs8*)&Wfrag[0][t][lane][0];
        const bs8 w1 = *(const bs8*)&Wfrag[1][t][lane][0];
        c = __builtin_amdgcn_mfma_f32_16x16x32_bf16(a0, w0, c, 0, 0, 0);
        c = __builtin_amdgcn_mfma_f32_16x16x32_bf16(a1, w1, c, 0, 0, 0);
        float p = 0.0f;                     // sum_m at1[m]*sig(C[m][col]); row = lg*4+r
        #pragma unroll
        for (int r = 0; r < 4; ++r)
            p = fmaf(__shfl(at1r, lg * 4 + r), fsig(c[r]), p);
        p += __shfl_xor(p, 16);
        p += __shfl_xor(p, 32);
        agg2r[t] = p;
    }

    Xl[wv][0][lane] = f2bf(x0);             // x0 into row 0 (rows 1-15 garbage, unused)
    C_FENCE();                              // x0 store before P2 reads (RAW)

    // P2: h0 via MFMA on row 0
    float x2v[4];
    {
        const bs8 b0 = *(const bs8*)&Xl[wv][lr][lg * 8];
        const bs8 b1 = *(const bs8*)&Xl[wv][lr][lg * 8 + 32];
        #pragma unroll
        for (int t = 0; t < 4; ++t) {
            f32x4 c; c[0] = bj[t]; c[1] = bj[t]; c[2] = bj[t]; c[3] = bj[t];
            const bs8 w0 = *(const bs8*)&Wfrag[0][t][lane][0];
            const bs8 w1 = *(const bs8*)&Wfrag[1][t][lane][0];
            c = __builtin_amdgcn_mfma_f32_16x16x32_bf16(b0, w0, c, 0, 0, 0);
            c = __builtin_amdgcn_mfma_f32_16x16x32_bf16(b1, w1, c, 0, 0, 0);
            x2v[t] = fsig(c[0]) + agg2r[t]; // meaningful at lanes<16 (row 0)
        }
    }

    C_FENCE();                              // P2 loads BEFORE x2 stores (WAR)
    #pragma unroll
    for (int t = 0; t < 4; ++t)
        if (lane < 16) Xl[wv][0][t * 16 + lane] = f2bf(x2v[t]);
    C_FENCE();                              // x2 stores before P3 reads (RAW)

    // P3: item via MFMA + final dot
    float pv = 0.0f;
    {
        const bs8 b0 = *(const bs8*)&Xl[wv][lr][lg * 8];
        const bs8 b1 = *(const bs8*)&Xl[wv][lr][lg * 8 + 32];
        #pragma unroll
        for (int t = 0; t < 4; ++t) {
            f32x4 c; c[0] = bj[t]; c[1] = bj[t]; c[2] = bj[t]; c[3] = bj[t];
            const bs8 w0 = *(const bs8*)&Wfrag[0][t][lane][0];
            const bs8 w1 = *(const bs8*)&Wfrag[1][t][lane][0];
            c = __builtin_amdgcn_mfma_f32_16x16x32_bf16(b0, w0, c, 0, 0, 0);
            c = __builtin_amdgcn_mfma_f32_16x16x32_bf16(b1, w1, c, 0, 0, 0);
            const float uc = __shfl(user, t * 16 + lr);
            if (lane < 16) pv = fmaf(uc, ftanh(c[0]), pv);
        }
    }
    pv += __shfl_xor(pv, 1);
    pv += __shfl_xor(pv, 2);
    pv += __shfl_xor(pv, 4);
    pv += __shfl_xor(pv, 8);
    if (lane == 0) out[b] = fsig(pv);
}

// ============ last-resort fallback: round-8 fused kernel ==============
__global__ __launch_bounds__(256) void kgcn_fused(
    const int* __restrict__ u, const int* __restrict__ v,
    const int* __restrict__ adj_ent, const int* __restrict__ adj_rel,
    const float* __restrict__ usr_emb, const float* __restrict__ rel_emb,
    const float* __restrict__ ent_emb, const float* __restrict__ W,
    const float* __restrict__ bias, float* __restrict__ out, int B)
{
    __shared__ __align__(16) ushort Wfrag[2][4][64][8];
    __shared__ __align__(16) ushort Xl[4][16][72];

    const int tid  = threadIdx.x;
    const int lane = tid & 63;
    const int wv   = tid >> 6;
    const int lr   = lane & 15;
    const int lg   = lane >> 4;

    {
        const int col = wv * 16 + lr;
        bs8 p0, p1;
        #pragma unroll
        for (int i = 0; i < 8; ++i) {
            p0[i] = (short)f2bf(W[(lg * 8 + i) * DIM + col]);
            p1[i] = (short)f2bf(W[(lg * 8 + i + 32) * DIM + col]);
        }
        *(bs8*)&Wfrag[0][wv][lane][0] = p0;
        *(bs8*)&Wfrag[1][wv][lane][0] = p1;
    }
    const float biasr = bias[lane];
    __syncthreads();

    const int   b     = blockIdx.x * 4 + wv;
    const int   e0    = v[b];
    const float user  = usr_emb[(size_t)u[b] * DIM + lane];
    const float ent0v = ent_emb[(size_t)e0 * DIM + lane];

    float ursr;
    {
        const int r  = lane & 31;
        const int hb = lane & 32;
        float s = 0.0f;
        #pragma unroll
        for (int dd = 0; dd < 32; ++dd)
            s = fmaf(__shfl(user, hb + dd), rel_emb[r * DIM + hb + dd], s);
        s += __shfl_xor(s, 32);
        ursr = s;
    }
    int e1r; float at1r;
    {
        e1r  = adj_ent[e0 * KF + lr];
        at1r = softmax16(__shfl(ursr, adj_rel[e0 * KF + lr]));
    }
    int e2r[4]; float at2r[4];
    #pragma unroll
    for (int it = 0; it < 4; ++it) {
        const int m  = it * 4 + lg;
        const int em = __shfl(e1r, m);
        e2r[it]  = adj_ent[em * KF + lr];
        at2r[it] = softmax16(__shfl(ursr, adj_rel[em * KF + lr]));
    }

    float agg0p = 0.0f;
    #pragma unroll
    for (int qo = 0; qo < 4; ++qo) {
        #pragma unroll 1
        for (int qi = 0; qi < 4; ++qi) {
            const int q = qo * 4 + qi;
            float rows[KF + 1];
            #pragma unroll
            for (int k = 0; k < KF; ++k) {
                const int e = __builtin_amdgcn_readlane(e2r[qo], qi * 16 + k);
                rows[k] = ent_emb[(size_t)e * DIM + lane];
            }
            rows[KF] = ent_emb[(size_t)__builtin_amdgcn_readlane(e1r, q) * DIM + lane];
            float g0 = 0.0f, g1 = 0.0f, g2 = 0.0f, g3 = 0.0f;
            #pragma unroll
            for (int k = 0; k < KF; k += 4) {
                g0 = fmaf(rdlane_f(at2r[qo], qi * 16 + k + 0), rows[k + 0], g0);
                g1 = fmaf(rdlane_f(at2r[qo], qi * 16 + k + 1), rows[k + 1], g1);
                g2 = fmaf(rdlane_f(at2r[qo], qi * 16 + k + 2), rows[k + 2], g2);
                g3 = fmaf(rdlane_f(at2r[qo], qi * 16 + k + 3), rows[k + 3], g3);
            }
            agg0p = fmaf(rdlane_f(at1r, q), rows[KF], agg0p);
            Xl[wv][q][lane] = f2bf(rows[KF] + ((g0 + g1) + (g2 + g3)));
        }
    }
    C_FENCE();

    float bj[4];
    #pragma unroll
    for (int t = 0; t < 4; ++t) bj[t] = __shfl(biasr, t * 16 + lr);

    float agg2r[4];
    {
        const bs8 a0 = *(const bs8*)&Xl[wv][lr][lg * 8];
        const bs8 a1 = *(const bs8*)&Xl[wv][lr][lg * 8 + 32];
        #pragma unroll
        for (int t = 0; t < 4; ++t) {
            f32x4 c; c[0] = bj[t]; c[1] = bj[t]; c[2] = bj[t]; c[3] = bj[t];
            const bs8 w0 = *(const bs8*)&Wfrag[0][t][lane][0];
            const bs8 w1 = *(const bs8*)&Wfrag[1][t][lane][0];
            c = __builtin_amdgcn_mfma_f32_16x16x32_bf16(a0, w0, c, 0, 0, 0);
            c = __builtin_amdgcn_mfma_f32_16x16x32_bf16(a1, w1, c, 0, 0, 0);
            float p = 0.0f;
            #pragma unroll
            for (int r = 0; r < 4; ++r)
                p = fmaf(__shfl(at1r, lg * 4 + r), fsig(c[r]), p);
            p += __shfl_xor(p, 16);
            p += __shfl_xor(p, 32);
            agg2r[t] = p;
        }
    }
    C_FENCE();
    Xl[wv][0][lane] = f2bf(ent0v + agg0p);
    C_FENCE();
    float x2v[4];
    {
        const bs8 a0 = *(const bs8*)&Xl[wv][lr][lg * 8];
        const bs8 a1 = *(const bs8*)&Xl[wv][lr][lg * 8 + 32];
        #pragma unroll
        for (int t = 0; t < 4; ++t) {
            f32x4 c; c[0] = bj[t]; c[1] = bj[t]; c[2] = bj[t]; c[3] = bj[t];
            const bs8 w0 = *(const bs8*)&Wfrag[0][t][lane][0];
            const bs8 w1 = *(const bs8*)&Wfrag[1][t][lane][0];
            c = __builtin_amdgcn_mfma_f32_16x16x32_bf16(a0, w0, c, 0, 0, 0);
            c = __builtin_amdgcn_mfma_f32_16x16x32_bf16(a1, w1, c, 0, 0, 0);
            x2v[t] = fsig(c[0]) + agg2r[t];
        }
    }
    C_FENCE();
    #pragma unroll
    for (int t = 0; t < 4; ++t)
        if (lane < 16) Xl[wv][0][t * 16 + lane] = f2bf(x2v[t]);
    C_FENCE();
    float pv = 0.0f;
    {
        const bs8 a0 = *(const bs8*)&Xl[wv][lr][lg * 8];
        const bs8 a1 = *(const bs8*)&Xl[wv][lr][lg * 8 + 32];
        #pragma unroll
        for (int t = 0; t < 4; ++t) {
            f32x4 c; c[0] = bj[t]; c[1] = bj[t]; c[2] = bj[t]; c[3] = bj[t];
            const bs8 w0 = *(const bs8*)&Wfrag[0][t][lane][0];
            const bs8 w1 = *(const bs8*)&Wfrag[1][t][lane][0];
            c = __builtin_amdgcn_mfma_f32_16x16x32_bf16(a0, w0, c, 0, 0, 0);
            c = __builtin_amdgcn_mfma_f32_16x16x32_bf16(a1, w1, c, 0, 0, 0);
            const float uc = __shfl(user, t * 16 + lr);
            if (lane < 16) pv = fmaf(uc, ftanh(c[0]), pv);
        }
    }
    pv += __shfl_xor(pv, 1);
    pv += __shfl_xor(pv, 2);
    pv += __shfl_xor(pv, 4);
    pv += __shfl_xor(pv, 8);
    if (lane == 0) out[b] = fsig(pv);
}

extern "C" void kernel_launch(void* const* d_in, const int* in_sizes, int n_in,
                              void* d_out, int out_size, void* d_ws, size_t ws_size,
                              hipStream_t stream) {
    const int*   u       = (const int*)d_in[0];
    const int*   v       = (const int*)d_in[1];
    const int*   adj_ent = (const int*)d_in[2];
    const int*   adj_rel = (const int*)d_in[3];
    const float* usr_emb = (const float*)d_in[4];
    const float* rel_emb = (const float*)d_in[5];
    const float* ent_emb = (const float*)d_in[6];
    const float* W       = (const float*)d_in[7];
    const float* bias    = (const float*)d_in[8];
    float* out = (float*)d_out;

    const int B  = in_sizes[0];
    const int NE = in_sizes[2] / KF;

    // ws layout: urs[B*32 f32] | e1[B*16 i32] | X[B*16*64 bf16] | ent_bf[NE*64 bf16]
    const size_t off_urs = 0;
    const size_t off_e1  = off_urs + (size_t)B * 32 * sizeof(float);
    const size_t off_X   = off_e1  + (size_t)B * KF * sizeof(int);
    const size_t off_eb  = off_X   + (size_t)B * KF * DIM * sizeof(ushort);
    const size_t need_sp = off_eb;
    const size_t need_fl = off_eb  + (size_t)NE * DIM * sizeof(ushort);

    float*  urs_ws = (float*)((char*)d_ws + off_urs);
    int*    e1_ws  = (int*)  ((char*)d_ws + off_e1);
    ushort* Xws    = (ushort*)((char*)d_ws + off_X);
    ushort* ent_bf = (ushort*)((char*)d_ws + off_eb);

    if (ws_size >= need_fl) {
        const long n8 = (long)NE * DIM / 8;
        const int  gcv = (int)((n8 + 255) / 256);
        const int  gpre = B / 4;
        k_convert_pre<<<(gcv > gpre ? gcv : gpre), 256, 0, stream>>>(
            ent_emb, ent_bf, n8, u, v, adj_ent, usr_emb, rel_emb, urs_ws, e1_ws, B);
        k_nodes<true><<<(B * KF) / 4, 256, 0, stream>>>(
            adj_ent, adj_rel, ent_emb, ent_bf, urs_ws, e1_ws, Xws);
        k_tail<true><<<B / 4, 256, 0, stream>>>(
            u, v, adj_rel, usr_emb, ent_emb, ent_bf, W, bias, urs_ws, e1_ws, Xws, out);
    } else if (ws_size >= need_sp) {
        k_convert_pre<<<B / 4, 256, 0, stream>>>(
            ent_emb, ent_bf, 0, u, v, adj_ent, usr_emb, rel_emb, urs_ws, e1_ws, B);
        k_nodes<false><<<(B * KF) / 4, 256, 0, stream>>>(
            adj_ent, adj_rel, ent_emb, ent_bf, urs_ws, e1_ws, Xws);
        k_tail<false><<<B / 4, 256, 0, stream>>>(
            u, v, adj_rel, usr_emb, ent_emb, ent_bf, W, bias, urs_ws, e1_ws, Xws, out);
    } else {
        kgcn_fused<<<B / 4, 256, 0, stream>>>(u, v, adj_ent, adj_rel,
                                              usr_emb, rel_emb, ent_emb,
                                              W, bias, out, B);
    }
}